// Round 6
// baseline (122.523 us; speedup 1.0000x reference)
//
#include <hip/hip_runtime.h>

// CrossNet, two-phase streaming:
//   cf[row] = 1+s0+s1+s2 where a_j = x0[row].w_j ; s0=a0 ;
//             s1=(1+s0)a1+t1 ; s2=(1+s0+s1)a2+t2 ; t1=B0.w1 ; t2=(B0+B1).w2
//   out[row] = x0[row]*cf[row] + (B0+B1+B2)
//
// Pass 1: pure READ stream (64 MiB x0) + butterfly -> cf[16384] in workspace.
//         Leaves x0 resident in the 256 MiB memory-side Infinity Cache.
// Pass 2: pure WRITE stream: re-reads x0 (LLC-hit), scales, adds bs, stores.
//         No reductions, no DS, max MLP.
// Decouples the read-phase from the write-phase so each runs at its
// single-stream peak instead of a finely interleaved R/W mix (~4.1 TB/s).

#define CN_BATCH 16384
#define CN_DIM   1024

typedef float f32x4 __attribute__((ext_vector_type(4)));

__device__ __forceinline__ float fma4(f32x4 x, f32x4 w, float acc) {
    acc = fmaf(x.x, w.x, acc); acc = fmaf(x.y, w.y, acc);
    acc = fmaf(x.z, w.z, acc); acc = fmaf(x.w, w.w, acc);
    return acc;
}

// ================= pass 1: cf per row (read-only stream) =================
#define P1_WAVES       4
#define P1_GROUPS      4
#define P1_GROUP_ROWS  2
#define P1_ROWS_WAVE   (P1_GROUPS * P1_GROUP_ROWS)               // 8
#define P1_BLOCKS      (CN_BATCH / (P1_WAVES * P1_ROWS_WAVE))    // 512

__global__ __launch_bounds__(256, 2) void
crossnet_pass1(const float* __restrict__ x0, const float* __restrict__ W,
               const float* __restrict__ B,  float* __restrict__ cf)
{
    const int tid  = threadIdx.x;
    const int wave = tid >> 6;
    const int lane = tid & 63;
    const int off0 = lane * 4;

    const size_t row0 = ((size_t)blockIdx.x * P1_WAVES + wave) * P1_ROWS_WAVE;
    const float* __restrict__ xr = x0 + row0 * CN_DIM;

    // group-0 x loads first (longest latency leads)
    f32x4 cur[P1_GROUP_ROWS][4], nxt[P1_GROUP_ROWS][4];
#pragma unroll
    for (int r = 0; r < P1_GROUP_ROWS; ++r)
#pragma unroll
        for (int c = 0; c < 4; ++c)
            cur[r][c] = *reinterpret_cast<const f32x4*>(xr + r * CN_DIM + c * 256 + off0);

    // W once per wave; t1/t2 partials from B (inside x-load shadow)
    f32x4 w0[4], w1[4], w2[4];
    float t1 = 0.f, t2 = 0.f;
#pragma unroll
    for (int c = 0; c < 4; ++c) {
        const int off = c * 256 + off0;
        w0[c] = *reinterpret_cast<const f32x4*>(W + 0 * CN_DIM + off);
        w1[c] = *reinterpret_cast<const f32x4*>(W + 1 * CN_DIM + off);
        w2[c] = *reinterpret_cast<const f32x4*>(W + 2 * CN_DIM + off);
        const f32x4 b0 = *reinterpret_cast<const f32x4*>(B + 0 * CN_DIM + off);
        const f32x4 b1 = *reinterpret_cast<const f32x4*>(B + 1 * CN_DIM + off);
        t1 = fma4(b0, w1[c], t1);
        t2 = fma4(b0 + b1, w2[c], t2);
    }

#pragma unroll
    for (int g = 0; g < P1_GROUPS; ++g) {
        if (g + 1 < P1_GROUPS) {
#pragma unroll
            for (int r = 0; r < P1_GROUP_ROWS; ++r)
#pragma unroll
                for (int c = 0; c < 4; ++c)
                    nxt[r][c] = *reinterpret_cast<const f32x4*>(
                        xr + (size_t)((g + 1) * P1_GROUP_ROWS + r) * CN_DIM + c * 256 + off0);
        }

        float a[P1_GROUP_ROWS][3];
#pragma unroll
        for (int r = 0; r < P1_GROUP_ROWS; ++r) { a[r][0] = a[r][1] = a[r][2] = 0.f; }
#pragma unroll
        for (int c = 0; c < 4; ++c)
#pragma unroll
            for (int r = 0; r < P1_GROUP_ROWS; ++r) {
                a[r][0] = fma4(cur[r][c], w0[c], a[r][0]);
                a[r][1] = fma4(cur[r][c], w1[c], a[r][1]);
                a[r][2] = fma4(cur[r][c], w2[c], a[r][2]);
            }

        // one butterfly: 6 row chains (+ t1,t2 fused on first group)
#pragma unroll
        for (int o = 1; o < 64; o <<= 1) {
#pragma unroll
            for (int r = 0; r < P1_GROUP_ROWS; ++r) {
                a[r][0] += __shfl_xor(a[r][0], o, 64);
                a[r][1] += __shfl_xor(a[r][1], o, 64);
                a[r][2] += __shfl_xor(a[r][2], o, 64);
            }
            if (g == 0) {
                t1 += __shfl_xor(t1, o, 64);
                t2 += __shfl_xor(t2, o, 64);
            }
        }

        if (lane == 0) {
#pragma unroll
            for (int r = 0; r < P1_GROUP_ROWS; ++r) {
                const float s0 = a[r][0];
                const float s1 = fmaf(1.f + s0, a[r][1], t1);
                const float s2 = fmaf(1.f + s0 + s1, a[r][2], t2);
                cf[row0 + (size_t)(g * P1_GROUP_ROWS + r)] = 1.f + s0 + s1 + s2;
            }
        }

#pragma unroll
        for (int r = 0; r < P1_GROUP_ROWS; ++r)
#pragma unroll
            for (int c = 0; c < 4; ++c)
                cur[r][c] = nxt[r][c];
    }
}

// ================= pass 2: out = x0*cf + bs (write stream) =================
#define P2_WAVES     4
#define P2_ROWS_WAVE 2
#define P2_BLOCKS    (CN_BATCH / (P2_WAVES * P2_ROWS_WAVE))     // 2048

__global__ __launch_bounds__(256, 4) void
crossnet_pass2(const float* __restrict__ x0, const float* __restrict__ B,
               const float* __restrict__ cf, float* __restrict__ out)
{
    const int tid  = threadIdx.x;
    const int wave = tid >> 6;
    const int lane = tid & 63;
    const int off0 = lane * 4;

    const size_t row0 = ((size_t)blockIdx.x * P2_WAVES + wave) * P2_ROWS_WAVE;
    const float* __restrict__ xr = x0 + row0 * CN_DIM;

    // x loads first (LLC-resident from pass 1)
    f32x4 xv[P2_ROWS_WAVE][4];
#pragma unroll
    for (int r = 0; r < P2_ROWS_WAVE; ++r)
#pragma unroll
        for (int c = 0; c < 4; ++c)
            xv[r][c] = *reinterpret_cast<const f32x4*>(xr + r * CN_DIM + c * 256 + off0);

    // wave-uniform cf scalars (L2-hot broadcast)
    const float c0 = cf[row0];
    const float c1 = cf[row0 + 1];

    // bs = B0+B1+B2 (L2-hot, inside x-load shadow)
    f32x4 bs[4];
#pragma unroll
    for (int c = 0; c < 4; ++c) {
        const int off = c * 256 + off0;
        const f32x4 b0 = *reinterpret_cast<const f32x4*>(B + 0 * CN_DIM + off);
        const f32x4 b1 = *reinterpret_cast<const f32x4*>(B + 1 * CN_DIM + off);
        const f32x4 b2 = *reinterpret_cast<const f32x4*>(B + 2 * CN_DIM + off);
        bs[c] = b0 + b1 + b2;
    }

    const float cfr[P2_ROWS_WAVE] = { c0, c1 };
#pragma unroll
    for (int r = 0; r < P2_ROWS_WAVE; ++r) {
        float* __restrict__ orow = out + (row0 + (size_t)r) * CN_DIM;
#pragma unroll
        for (int c = 0; c < 4; ++c) {
            f32x4 o;
            o.x = fmaf(xv[r][c].x, cfr[r], bs[c].x);
            o.y = fmaf(xv[r][c].y, cfr[r], bs[c].y);
            o.z = fmaf(xv[r][c].z, cfr[r], bs[c].z);
            o.w = fmaf(xv[r][c].w, cfr[r], bs[c].w);
            *reinterpret_cast<f32x4*>(orow + c * 256 + off0) = o;
        }
    }
}

// ================= fallback: single-pass (round-5 kernel) =================
__global__ __launch_bounds__(256, 2) void
crossnet_single(const float* __restrict__ x0, const float* __restrict__ W,
                const float* __restrict__ B,  float* __restrict__ out)
{
    const int tid  = threadIdx.x;
    const int wave = tid >> 6;
    const int lane = tid & 63;
    const int off0 = lane * 4;

    const size_t row0 = ((size_t)blockIdx.x * P1_WAVES + wave) * P1_ROWS_WAVE;
    const float* __restrict__ xr = x0 + row0 * CN_DIM;

    f32x4 cur[P1_GROUP_ROWS][4], nxt[P1_GROUP_ROWS][4];
#pragma unroll
    for (int r = 0; r < P1_GROUP_ROWS; ++r)
#pragma unroll
        for (int c = 0; c < 4; ++c)
            cur[r][c] = *reinterpret_cast<const f32x4*>(xr + r * CN_DIM + c * 256 + off0);

    f32x4 w0[4], w1[4], w2[4], bs[4];
    float t1 = 0.f, t2 = 0.f;
#pragma unroll
    for (int c = 0; c < 4; ++c) {
        const int off = c * 256 + off0;
        w0[c] = *reinterpret_cast<const f32x4*>(W + 0 * CN_DIM + off);
        w1[c] = *reinterpret_cast<const f32x4*>(W + 1 * CN_DIM + off);
        w2[c] = *reinterpret_cast<const f32x4*>(W + 2 * CN_DIM + off);
        const f32x4 b0 = *reinterpret_cast<const f32x4*>(B + 0 * CN_DIM + off);
        const f32x4 b1 = *reinterpret_cast<const f32x4*>(B + 1 * CN_DIM + off);
        const f32x4 b2 = *reinterpret_cast<const f32x4*>(B + 2 * CN_DIM + off);
        bs[c] = b0 + b1 + b2;
        t1 = fma4(b0, w1[c], t1);
        t2 = fma4(b0 + b1, w2[c], t2);
    }

#pragma unroll
    for (int g = 0; g < P1_GROUPS; ++g) {
        if (g + 1 < P1_GROUPS) {
#pragma unroll
            for (int r = 0; r < P1_GROUP_ROWS; ++r)
#pragma unroll
                for (int c = 0; c < 4; ++c)
                    nxt[r][c] = *reinterpret_cast<const f32x4*>(
                        xr + (size_t)((g + 1) * P1_GROUP_ROWS + r) * CN_DIM + c * 256 + off0);
        }

        float a[P1_GROUP_ROWS][3];
#pragma unroll
        for (int r = 0; r < P1_GROUP_ROWS; ++r) { a[r][0] = a[r][1] = a[r][2] = 0.f; }
#pragma unroll
        for (int c = 0; c < 4; ++c)
#pragma unroll
            for (int r = 0; r < P1_GROUP_ROWS; ++r) {
                a[r][0] = fma4(cur[r][c], w0[c], a[r][0]);
                a[r][1] = fma4(cur[r][c], w1[c], a[r][1]);
                a[r][2] = fma4(cur[r][c], w2[c], a[r][2]);
            }
#pragma unroll
        for (int o = 1; o < 64; o <<= 1) {
#pragma unroll
            for (int r = 0; r < P1_GROUP_ROWS; ++r) {
                a[r][0] += __shfl_xor(a[r][0], o, 64);
                a[r][1] += __shfl_xor(a[r][1], o, 64);
                a[r][2] += __shfl_xor(a[r][2], o, 64);
            }
            if (g == 0) { t1 += __shfl_xor(t1, o, 64); t2 += __shfl_xor(t2, o, 64); }
        }
#pragma unroll
        for (int r = 0; r < P1_GROUP_ROWS; ++r) {
            const float s0 = a[r][0];
            const float s1 = fmaf(1.f + s0, a[r][1], t1);
            const float s2 = fmaf(1.f + s0 + s1, a[r][2], t2);
            const float cfv = 1.f + s0 + s1 + s2;
            float* __restrict__ orow = out + (row0 + (size_t)(g * P1_GROUP_ROWS + r)) * CN_DIM;
#pragma unroll
            for (int c = 0; c < 4; ++c) {
                f32x4 o;
                o.x = fmaf(cur[r][c].x, cfv, bs[c].x);
                o.y = fmaf(cur[r][c].y, cfv, bs[c].y);
                o.z = fmaf(cur[r][c].z, cfv, bs[c].z);
                o.w = fmaf(cur[r][c].w, cfv, bs[c].w);
                *reinterpret_cast<f32x4*>(orow + c * 256 + off0) = o;
            }
        }
#pragma unroll
        for (int r = 0; r < P1_GROUP_ROWS; ++r)
#pragma unroll
            for (int c = 0; c < 4; ++c)
                cur[r][c] = nxt[r][c];
    }
}

extern "C" void kernel_launch(void* const* d_in, const int* in_sizes, int n_in,
                              void* d_out, int out_size, void* d_ws, size_t ws_size,
                              hipStream_t stream)
{
    const float* x0 = (const float*)d_in[0];   // [16384, 1024]
    const float* W  = (const float*)d_in[1];   // [3, 1024]
    const float* B  = (const float*)d_in[2];   // [3, 1024]
    float* out      = (float*)d_out;           // [16384, 1024]

    if (d_ws != nullptr && ws_size >= (size_t)CN_BATCH * sizeof(float)) {
        float* cf = (float*)d_ws;              // [16384]
        crossnet_pass1<<<dim3(P1_BLOCKS), dim3(256), 0, stream>>>(x0, W, B, cf);
        crossnet_pass2<<<dim3(P2_BLOCKS), dim3(256), 0, stream>>>(x0, B, cf, out);
    } else {
        crossnet_single<<<dim3(P1_BLOCKS), dim3(256), 0, stream>>>(x0, W, B, out);
    }
}

// Round 7
// 119.828 us; speedup vs baseline: 1.0225x; 1.0225x over previous
//
#include <hip/hip_runtime.h>

// CrossNet collapsed analytically:
//   a_j = x0 . w_j ; s0=a0 ; s1=(1+s0)a1 + t1 ; s2=(1+s0+s1)a2 + t2
//   out = x0*(1+s0+s1+s2) + bs
// t1 = B0.w1, t2 = (B0+B1).w2, bs = B0+B1+B2 (row-independent, per-wave).
//
// Key change vs R5: the 64-lane reduction is a DPP chain (pure VALU,
// ~50 cy latency, ZERO ds_swizzle) instead of a 6-stage ds_swizzle
// butterfly (~720 cy dependent DS latency). Result lands in lane 63 and
// is moved to an SGPR via v_readlane — cf is wave-uniform by nature.
// With the reduce tail tiny, pipeline state shrinks -> 128-VGPR budget
// -> 16 waves/CU (1024 blocks x 256 thr, all resident), 4 rows/wave,
// 1-row prefetch keeps HBM loads in flight through the reduce/store.

#define CN_BATCH 16384
#define CN_DIM   1024

#define WAVES_PER_BLOCK 4
#define ROWS_PER_WAVE   4
#define ROWS_PER_BLOCK  (WAVES_PER_BLOCK * ROWS_PER_WAVE)   // 16
#define GRID_BLOCKS     (CN_BATCH / ROWS_PER_BLOCK)         // 1024

typedef float f32x4 __attribute__((ext_vector_type(4)));

__device__ __forceinline__ float fma4(f32x4 x, f32x4 w, float acc) {
    acc = fmaf(x.x, w.x, acc); acc = fmaf(x.y, w.y, acc);
    acc = fmaf(x.z, w.z, acc); acc = fmaf(x.w, w.w, acc);
    return acc;
}

// x + dpp_mov(x) with old=0: lanes with invalid/unselected source add 0.
#define DPP_ADD(x, ctrl, rmask)                                            \
    ((x) + __int_as_float(__builtin_amdgcn_update_dpp(                     \
         0, __float_as_int(x), (ctrl), (rmask), 0xf, false)))

// rocPRIM-style wave64 sum: full sum ends in lane 63 (pure VALU, no DS).
// row_shr:N = 0x110|N ; row_bcast:15 = 0x142 ; row_bcast:31 = 0x143
__device__ __forceinline__ float wave_sum63(float x) {
    x = DPP_ADD(x, 0x111, 0xf);   // += lane-1   (row_shr:1)
    x = DPP_ADD(x, 0x112, 0xf);   // += lane-2   (row_shr:2)
    x = DPP_ADD(x, 0x114, 0xf);   // += lane-4   (row_shr:4)
    x = DPP_ADD(x, 0x118, 0xf);   // += lane-8   (row_shr:8) -> lane15 of each row16 = row sum
    x = DPP_ADD(x, 0x142, 0xa);   // row_bcast:15 into rows 1,3
    x = DPP_ADD(x, 0x143, 0xc);   // row_bcast:31 into rows 2,3 -> lane 63 = total
    return x;
}

__device__ __forceinline__ float bcast63(float x) {
    return __int_as_float(__builtin_amdgcn_readlane(__float_as_int(x), 63));
}

__global__ __launch_bounds__(256, 4) void
crossnet_kernel(const float* __restrict__ x0,
                const float* __restrict__ W,
                const float* __restrict__ B,
                float* __restrict__ out)
{
    const int tid  = threadIdx.x;
    const int wave = tid >> 6;
    const int lane = tid & 63;
    const int off0 = lane * 4;              // 16B-aligned per-lane column

    const size_t row0 = ((size_t)blockIdx.x * WAVES_PER_BLOCK + wave) * ROWS_PER_WAVE;
    const float* __restrict__ xr = x0 + row0 * CN_DIM;

    // ---- issue row-0 x loads FIRST (longest latency leads) ----
    f32x4 cur[4], nxt[4];
#pragma unroll
    for (int c = 0; c < 4; ++c)
        cur[c] = *reinterpret_cast<const f32x4*>(xr + c * 256 + off0);

    // ---- W/B once per wave (L2-hot, inside the x-load shadow) ----
    f32x4 w0[4], w1[4], w2[4], bs[4];
    float t1 = 0.f, t2 = 0.f;
#pragma unroll
    for (int c = 0; c < 4; ++c) {
        const int off = c * 256 + off0;
        w0[c] = *reinterpret_cast<const f32x4*>(W + 0 * CN_DIM + off);
        w1[c] = *reinterpret_cast<const f32x4*>(W + 1 * CN_DIM + off);
        w2[c] = *reinterpret_cast<const f32x4*>(W + 2 * CN_DIM + off);
        const f32x4 b0 = *reinterpret_cast<const f32x4*>(B + 0 * CN_DIM + off);
        const f32x4 b1 = *reinterpret_cast<const f32x4*>(B + 1 * CN_DIM + off);
        const f32x4 b2 = *reinterpret_cast<const f32x4*>(B + 2 * CN_DIM + off);
        bs[c] = b0 + b1 + b2;
        t1 = fma4(b0, w1[c], t1);
        t2 = fma4(b0 + b1, w2[c], t2);
    }
    const float t1s = bcast63(wave_sum63(t1));
    const float t2s = bcast63(wave_sum63(t2));

    // ---- 4 rows, 1-row software pipeline ----
#pragma unroll
    for (int r = 0; r < ROWS_PER_WAVE; ++r) {
        if (r + 1 < ROWS_PER_WAVE) {
#pragma unroll
            for (int c = 0; c < 4; ++c)
                nxt[c] = *reinterpret_cast<const f32x4*>(
                    xr + (size_t)(r + 1) * CN_DIM + c * 256 + off0);
        }

        // three dot partials (W register-resident)
        float a0 = 0.f, a1 = 0.f, a2 = 0.f;
#pragma unroll
        for (int c = 0; c < 4; ++c) {
            a0 = fma4(cur[c], w0[c], a0);
            a1 = fma4(cur[c], w1[c], a1);
            a2 = fma4(cur[c], w2[c], a2);
        }

        // DPP reduce, three chains interleaved (pure VALU, ~50 cy)
        a0 = wave_sum63(a0);
        a1 = wave_sum63(a1);
        a2 = wave_sum63(a2);
        const float s0 = bcast63(a0);
        const float A1 = bcast63(a1);
        const float A2 = bcast63(a2);

        const float s1 = fmaf(1.f + s0, A1, t1s);
        const float s2 = fmaf(1.f + s0 + s1, A2, t2s);
        const float cf = 1.f + s0 + s1 + s2;     // wave-uniform (SGPR)

        float* __restrict__ orow = out + (row0 + (size_t)r) * CN_DIM;
#pragma unroll
        for (int c = 0; c < 4; ++c) {
            f32x4 o;
            o.x = fmaf(cur[c].x, cf, bs[c].x);
            o.y = fmaf(cur[c].y, cf, bs[c].y);
            o.z = fmaf(cur[c].z, cf, bs[c].z);
            o.w = fmaf(cur[c].w, cf, bs[c].w);
            *reinterpret_cast<f32x4*>(orow + c * 256 + off0) = o;
        }

#pragma unroll
        for (int c = 0; c < 4; ++c) cur[c] = nxt[c];
    }
}

extern "C" void kernel_launch(void* const* d_in, const int* in_sizes, int n_in,
                              void* d_out, int out_size, void* d_ws, size_t ws_size,
                              hipStream_t stream)
{
    const float* x0 = (const float*)d_in[0];   // [16384, 1024]
    const float* W  = (const float*)d_in[1];   // [3, 1024]
    const float* B  = (const float*)d_in[2];   // [3, 1024]
    float* out      = (float*)d_out;           // [16384, 1024]

    dim3 grid(GRID_BLOCKS);                    // 1024 blocks = 4/CU, all resident
    dim3 block(WAVES_PER_BLOCK * 64);          // 256 threads, 16 waves/CU
    crossnet_kernel<<<grid, block, 0, stream>>>(x0, W, B, out);
}

// Round 8
// 116.477 us; speedup vs baseline: 1.0519x; 1.0288x over previous
//
#include <hip/hip_runtime.h>

// CrossNet collapsed analytically:
//   a_j = x0 . w_j ; s0=a0 ; s1=(1+s0)a1 + t1 ; s2=(1+s0+s1)a2 + t2
//   out = x0*(1+s0+s1+s2) + bs
// t1 = B0.w1, t2 = (B0+B1).w2, bs = B0+B1+B2 (row-independent, per-wave).
//
// 3-stage software pipeline (load / reduce / store are DIFFERENT rows):
//   iter r:  dots(r)          - covers tail of butterfly(r-1)
//            store(r-1)       - cf(r-1) ready; reduce latency OFF store path
//            load(r+2)        - into buffer freed by the store (mod-3 rotation)
//            butterfly(r)     - latency covered by next iter's dots
// Loads have 2 iterations of slack, butterfly has 1 iteration, stores never
// wait on a reduction. R5 geometry otherwise: 512 blocks x 256 thr (2/CU,
// all resident), 8 rows/wave, W/bs register-resident, shuffle butterfly.

#define CN_BATCH 16384
#define CN_DIM   1024

#define WAVES_PER_BLOCK 4
#define ROWS_PER_WAVE   8
#define ROWS_PER_BLOCK  (WAVES_PER_BLOCK * ROWS_PER_WAVE)   // 32
#define GRID_BLOCKS     (CN_BATCH / ROWS_PER_BLOCK)         // 512

typedef float f32x4 __attribute__((ext_vector_type(4)));

__device__ __forceinline__ float fma4(f32x4 x, f32x4 w, float acc) {
    acc = fmaf(x.x, w.x, acc); acc = fmaf(x.y, w.y, acc);
    acc = fmaf(x.z, w.z, acc); acc = fmaf(x.w, w.w, acc);
    return acc;
}

__global__ __launch_bounds__(256, 2) void
crossnet_kernel(const float* __restrict__ x0,
                const float* __restrict__ W,
                const float* __restrict__ B,
                float* __restrict__ out)
{
    const int tid  = threadIdx.x;
    const int wave = tid >> 6;
    const int lane = tid & 63;
    const int off0 = lane * 4;              // 16B-aligned per-lane column

    const size_t row0 = ((size_t)blockIdx.x * WAVES_PER_BLOCK + wave) * ROWS_PER_WAVE;
    const float* __restrict__ xr = x0 + row0 * CN_DIM;

    // ---- prologue: fill the 3-deep load pipeline (rows 0,1,2) ----
    f32x4 xb[3][4];                          // rotating row buffers
#pragma unroll
    for (int r = 0; r < 3; ++r)
#pragma unroll
        for (int c = 0; c < 4; ++c)
            xb[r][c] = *reinterpret_cast<const f32x4*>(xr + r * CN_DIM + c * 256 + off0);

    // ---- W/B once per wave (L2-hot, inside the x-load shadow) ----
    f32x4 w0[4], w1[4], w2[4], bs[4];
    float t1 = 0.f, t2 = 0.f;
#pragma unroll
    for (int c = 0; c < 4; ++c) {
        const int off = c * 256 + off0;
        w0[c] = *reinterpret_cast<const f32x4*>(W + 0 * CN_DIM + off);
        w1[c] = *reinterpret_cast<const f32x4*>(W + 1 * CN_DIM + off);
        w2[c] = *reinterpret_cast<const f32x4*>(W + 2 * CN_DIM + off);
        const f32x4 b0 = *reinterpret_cast<const f32x4*>(B + 0 * CN_DIM + off);
        const f32x4 b1 = *reinterpret_cast<const f32x4*>(B + 1 * CN_DIM + off);
        const f32x4 b2 = *reinterpret_cast<const f32x4*>(B + 2 * CN_DIM + off);
        bs[c] = b0 + b1 + b2;
        t1 = fma4(b0, w1[c], t1);
        t2 = fma4(b0 + b1, w2[c], t2);
    }

    // ---- row 0: dots + butterfly (t1,t2 chains fused, 5 chains, 6 stages) ----
    float a0 = 0.f, a1 = 0.f, a2 = 0.f;
#pragma unroll
    for (int c = 0; c < 4; ++c) {
        a0 = fma4(xb[0][c], w0[c], a0);
        a1 = fma4(xb[0][c], w1[c], a1);
        a2 = fma4(xb[0][c], w2[c], a2);
    }
#pragma unroll
    for (int o = 1; o < 64; o <<= 1) {
        a0 += __shfl_xor(a0, o, 64);
        a1 += __shfl_xor(a1, o, 64);
        a2 += __shfl_xor(a2, o, 64);
        t1 += __shfl_xor(t1, o, 64);
        t2 += __shfl_xor(t2, o, 64);
    }
    float s0 = a0;
    float s1 = fmaf(1.f + s0, a1, t1);
    float s2 = fmaf(1.f + s0 + s1, a2, t2);
    float cf_prev = 1.f + s0 + s1 + s2;      // cf(row 0)

    // ---- steady-state pipeline: r = 1..7 ----
#pragma unroll
    for (int r = 1; r < ROWS_PER_WAVE; ++r) {
        const int cbuf = r % 3;              // row r (reduce stage)
        const int sbuf = (r - 1) % 3;        // row r-1 (store stage)
        // note (r+2)%3 == sbuf: load reuses the buffer freed by the store

        // 1) dots(r): pure VALU, covers the tail of butterfly(r-1)
        a0 = 0.f; a1 = 0.f; a2 = 0.f;
#pragma unroll
        for (int c = 0; c < 4; ++c) {
            a0 = fma4(xb[cbuf][c], w0[c], a0);
            a1 = fma4(xb[cbuf][c], w1[c], a1);
            a2 = fma4(xb[cbuf][c], w2[c], a2);
        }

        // 2) store(r-1): cf_prev finished during the dots above
        {
            float* __restrict__ orow = out + (row0 + (size_t)(r - 1)) * CN_DIM;
#pragma unroll
            for (int c = 0; c < 4; ++c) {
                f32x4 o;
                o.x = fmaf(xb[sbuf][c].x, cf_prev, bs[c].x);
                o.y = fmaf(xb[sbuf][c].y, cf_prev, bs[c].y);
                o.z = fmaf(xb[sbuf][c].z, cf_prev, bs[c].z);
                o.w = fmaf(xb[sbuf][c].w, cf_prev, bs[c].w);
                *reinterpret_cast<f32x4*>(orow + c * 256 + off0) = o;
            }
        }

        // 3) load(r+2) into the buffer just freed (2 iterations of slack)
        if (r + 2 < ROWS_PER_WAVE) {
#pragma unroll
            for (int c = 0; c < 4; ++c)
                xb[sbuf][c] = *reinterpret_cast<const f32x4*>(
                    xr + (size_t)(r + 2) * CN_DIM + c * 256 + off0);
        }

        // 4) butterfly(r): latency covered by next iteration's dots
#pragma unroll
        for (int o = 1; o < 64; o <<= 1) {
            a0 += __shfl_xor(a0, o, 64);
            a1 += __shfl_xor(a1, o, 64);
            a2 += __shfl_xor(a2, o, 64);
        }
        s0 = a0;
        s1 = fmaf(1.f + s0, a1, t1);
        s2 = fmaf(1.f + s0 + s1, a2, t2);
        cf_prev = 1.f + s0 + s1 + s2;        // cf(row r)
    }

    // ---- epilogue: store row 7 ----
    {
        const int sbuf = (ROWS_PER_WAVE - 1) % 3;
        float* __restrict__ orow = out + (row0 + (size_t)(ROWS_PER_WAVE - 1)) * CN_DIM;
#pragma unroll
        for (int c = 0; c < 4; ++c) {
            f32x4 o;
            o.x = fmaf(xb[sbuf][c].x, cf_prev, bs[c].x);
            o.y = fmaf(xb[sbuf][c].y, cf_prev, bs[c].y);
            o.z = fmaf(xb[sbuf][c].z, cf_prev, bs[c].z);
            o.w = fmaf(xb[sbuf][c].w, cf_prev, bs[c].w);
            *reinterpret_cast<f32x4*>(orow + c * 256 + off0) = o;
        }
    }
}

extern "C" void kernel_launch(void* const* d_in, const int* in_sizes, int n_in,
                              void* d_out, int out_size, void* d_ws, size_t ws_size,
                              hipStream_t stream)
{
    const float* x0 = (const float*)d_in[0];   // [16384, 1024]
    const float* W  = (const float*)d_in[1];   // [3, 1024]
    const float* B  = (const float*)d_in[2];   // [3, 1024]
    float* out      = (float*)d_out;           // [16384, 1024]

    dim3 grid(GRID_BLOCKS);                    // 512 blocks = 2/CU, all resident
    dim3 block(WAVES_PER_BLOCK * 64);          // 256 threads
    crossnet_kernel<<<grid, block, 0, stream>>>(x0, W, B, out);
}